// Round 6
// baseline (200.048 us; speedup 1.0000x reference)
//
#include <hip/hip_runtime.h>
#include <math.h>

// PointLoss R5: ONE pixel per thread (9360 blocks x 256 = NPIX exactly).
// No per-thread loop => no cross-iteration vmcnt(0) serialization (the
// structural stall in R0-R4, which all converged to ~47-57 us regardless of
// ILP shape). Latency hiding comes from TLP: ~32 waves/CU cycling 4.6
// residency rounds. nrm/unc are streamed with the up-front batch (they only
// depend on p); only lastn/lastm/lastv remain in the dependent gather hop.
// Fast atan2/asin validated in R3/R4 (absmax 0.0).

namespace {
constexpr int B_ = 64, H_ = 52, W_ = 720;
constexpr int HW_ = H_ * W_;            // 37440
constexpr int NPIX = B_ * HW_;          // 2396160
constexpr int NT = 256;
constexpr int NB = NPIX / NT;           // 9360 exactly
constexpr float EPSF = 1e-8f;
constexpr float RAD2DEG = 57.29577951308232f;
}

__device__ __forceinline__ float atan_poly01(float z) {  // atan(z), z in [0,1]
    const float z2 = z * z;
    float r = fmaf(z2, -0.0117212f, 0.0526526f);
    r = fmaf(z2, r, -0.1164329f);
    r = fmaf(z2, r,  0.1935435f);
    r = fmaf(z2, r, -0.3326235f);
    r = fmaf(z2, r,  0.9999773f);
    return r * z;
}

__device__ __forceinline__ float atan2_fast(float y, float x) {
    const float ax = fabsf(x), ay = fabsf(y);
    const float mx = fmaxf(ax, ay), mn = fminf(ax, ay);
    const float z = mn * __builtin_amdgcn_rcpf(fmaxf(mx, 1e-37f));
    float a = atan_poly01(z);
    if (ay > ax) a = 1.5707964f - a;
    if (x < 0.0f) a = 3.1415927f - a;
    return copysignf(a, y);
}

__device__ __forceinline__ float asin_core(float x) {  // asin(x), x in [0,0.5]
    const float x2 = x * x;
    float r = fmaf(x2, 0.03038196f, 0.04464286f);
    r = fmaf(x2, r, 0.075f);
    r = fmaf(x2, r, 0.16666667f);
    return fmaf(x * x2, r, x);
}

__device__ __forceinline__ float asin_fast(float q) {  // q in [-1,1]
    const float a = fabsf(q);
    const float r1 = asin_core(a);
    const float s = sqrtf(fmaxf(0.5f * (1.0f - a), 0.0f));
    const float r2 = 1.5707964f - 2.0f * asin_core(s);
    const float r = (a > 0.5f) ? r2 : r1;
    return copysignf(r, q);
}

__global__ __launch_bounds__(NT) void pointloss_main(
    const float* __restrict__ v,
    const float* __restrict__ nrm,
    const float* __restrict__ unc,
    const float* __restrict__ nown,
    const float* __restrict__ conf,
    const float* __restrict__ lastn,
    const float* __restrict__ lastv,
    const int*   __restrict__ nowm,
    const int*   __restrict__ lastm,
    float* __restrict__ partials)     // SoA: [5][NB]
{
    const int p = blockIdx.x * NT + threadIdx.x;   // always < NPIX

    // ---- streaming loads: everything addressable by p, issued up front ----
    const float vx = v[3*p],    vy = v[3*p+1],    vz = v[3*p+2];
    const float ax = nown[3*p], ay = nown[3*p+1], az = nown[3*p+2];
    const int   mi = nowm[p];
    const float cf = conf[p];
    const float uv = unc[p];
    const float nx = nrm[3*p],  ny = nrm[3*p+1],  nz = nrm[3*p+2];

    const bool mask0 = (mi > 0) &&
                       ((fabsf(ax) + fabsf(ay) + fabsf(az)) != 0.0f);

    const float d2 = vx*vx + vy*vy + vz*vz + EPSF;
    const float q  = fminf(fmaxf(vz * __builtin_amdgcn_rsqf(d2), -1.f), 1.f);
    const float yaw   = atan2_fast(vy, vx) * RAD2DEG;
    const float pitch = asin_fast(q) * RAD2DEG;
    const float px = (180.0f - yaw) * 2.0f;
    const float py = (3.0f - pitch) * 2.0f;

    float s_m0 = 0.f, s_fov = 0.f, s_m = 0.f, s_icp = 0.f, s_ang = 0.f;
    if (mask0) {
        const float dx = px - fminf(fmaxf(px, 0.f), 719.0f);
        const float dy = py - fminf(fmaxf(py, 0.f), 51.0f);
        s_m0 = 1.0f;
        s_fov = dx*dx + dy*dy;
    }

    const float prx = rintf(px), pry = rintf(py);   // round-half-even
    const bool inb = (prx >= 0.f) && (prx < 720.f) &&
                     (pry >= 0.f) && (pry < 52.f);

    if (mask0 && inb && (cf >= 0.5f)) {
        // gi = batch_base + y*W + x  (avoid div: p - p%HW is batch base)
        const int gi = p - (p % HW_) + (int)pry * W_ + (int)prx;
        const float lx = lastn[3*gi], ly = lastn[3*gi+1], lz = lastn[3*gi+2];
        const int   lmv = lastm[gi];
        const float wx = lastv[3*gi], wy = lastv[3*gi+1], wz = lastv[3*gi+2];
        if ((lmv > 0) && ((fabsf(lx) + fabsf(ly) + fabsf(lz)) != 0.f)) {
            const float r  = lx*(vx-wx) + ly*(vy-wy) + lz*(vz-wz);
            const float dt = lx*nx + ly*ny + lz*nz;
            const float den = (lx*lx + ly*ly + lz*lz) *
                              (nx*nx + ny*ny + nz*nz) + EPSF;
            const float cosang = fabsf(dt) * __builtin_amdgcn_rsqf(den);
            s_m   = 1.0f;
            s_icp = uv * fabsf(r);
            s_ang = uv * (1.0f - cosang);
        }
    }

    // ---- block reduction ----
    #pragma unroll
    for (int off = 32; off > 0; off >>= 1) {
        s_m0  += __shfl_down(s_m0,  off);
        s_fov += __shfl_down(s_fov, off);
        s_m   += __shfl_down(s_m,   off);
        s_icp += __shfl_down(s_icp, off);
        s_ang += __shfl_down(s_ang, off);
    }
    __shared__ float red[NT / 64][5];
    const int lane = threadIdx.x & 63;
    const int wv   = threadIdx.x >> 6;
    if (lane == 0) {
        red[wv][0] = s_m0;  red[wv][1] = s_fov; red[wv][2] = s_m;
        red[wv][3] = s_icp; red[wv][4] = s_ang;
    }
    __syncthreads();
    if (threadIdx.x == 0) {
        float tt[5] = {0.f, 0.f, 0.f, 0.f, 0.f};
        for (int w2 = 0; w2 < NT / 64; ++w2)
            for (int c = 0; c < 5; ++c) tt[c] += red[w2][c];
        #pragma unroll
        for (int c = 0; c < 5; ++c)
            partials[c * NB + blockIdx.x] = tt[c];   // SoA for coalesced finalize
    }
}

__global__ __launch_bounds__(1024) void pointloss_finalize(
    const float* __restrict__ partials,   // [5][NB]
    const float* __restrict__ sx,
    const float* __restrict__ sq,
    float* __restrict__ out)
{
    double a[5] = {0, 0, 0, 0, 0};
    for (int i = threadIdx.x; i < NB; i += 1024) {
        #pragma unroll
        for (int c = 0; c < 5; ++c) a[c] += (double)partials[c * NB + i];
    }
    #pragma unroll
    for (int off = 32; off > 0; off >>= 1) {
        #pragma unroll
        for (int c = 0; c < 5; ++c) a[c] += __shfl_down(a[c], off);
    }
    __shared__ double red[16][5];
    const int lane = threadIdx.x & 63;
    const int wv   = threadIdx.x >> 6;
    if (lane == 0) {
        #pragma unroll
        for (int c = 0; c < 5; ++c) red[wv][c] = a[c];
    }
    __syncthreads();
    if (threadIdx.x == 0) {
        double t[5] = {0, 0, 0, 0, 0};
        for (int w2 = 0; w2 < 16; ++w2)
            for (int c = 0; c < 5; ++c) t[c] += red[w2][c];
        const double n0 = fmax(t[0], 1.0);
        const double n  = fmax(t[2], 1.0);
        const double sx0 = (double)sx[0], sq0 = (double)sq[0];
        const double total = exp(-sx0) * (t[3] / n) + sx0
                           + exp(-sq0) * (t[4] / n) + sq0
                           + t[1] / n0;   // LAMDA = 1, ANGRATE = 1
        out[0] = (float)total;
    }
}

extern "C" void kernel_launch(void* const* d_in, const int* in_sizes, int n_in,
                              void* d_out, int out_size, void* d_ws, size_t ws_size,
                              hipStream_t stream) {
    const float* v     = (const float*)d_in[0];
    const float* nrm   = (const float*)d_in[1];
    const float* unc   = (const float*)d_in[2];
    const float* nown  = (const float*)d_in[3];
    const float* conf  = (const float*)d_in[4];
    const float* lastn = (const float*)d_in[5];
    const float* lastv = (const float*)d_in[6];
    const float* sx    = (const float*)d_in[7];
    const float* sq    = (const float*)d_in[8];
    const int*   nowm  = (const int*)d_in[9];
    const int*   lastm = (const int*)d_in[10];

    float* partials = (float*)d_ws;  // 5*NB floats = 187 KB

    pointloss_main<<<NB, NT, 0, stream>>>(
        v, nrm, unc, nown, conf, lastn, lastv, nowm, lastm, partials);
    pointloss_finalize<<<1, 1024, 0, stream>>>(partials, sx, sq, (float*)d_out);
}